// Round 4
// baseline (95.196 us; speedup 1.0000x reference)
//
#include <hip/hip_runtime.h>

// Problem constants (match reference)
#define BB 8192
#define PP 2048
#define LL 1024
#define OO 1000
#define NB 512   // grid size; co-residency capacity with launch_bounds(256,4) is 1024

// ws float offsets
#define WS_COLSUM 0        // [1024]
#define WS_WSUM   1024     // [1000]
#define WS_PSQ    2048     // [1]
#define WS_SQPART 2112     // [256]
#define WS_BAR    3072     // 2 uints, zeroed by hipMemsetAsync each call
#define WS_PCOL   4096     // [64][1024]

// Hand-rolled grid barrier. bar[0]=arrival counter, bar[1]=generation.
// Device-scope atomics + __threadfence = documented cross-XCD mitigation.
// Counters are zeroed by a memset node before the kernel in every replay.
__device__ __forceinline__ void grid_barrier(unsigned* bar, unsigned gen) {
    __syncthreads();
    if (threadIdx.x == 0) {
        __threadfence();                       // release prior writes
        unsigned old = atomicAdd(&bar[0], 1u);
        if (old == NB - 1) {
            atomicExch(&bar[0], 0u);           // reset for next barrier (all arrived)
            __threadfence();
            atomicAdd(&bar[1], 1u);            // release
        } else {
            while (atomicAdd(&bar[1], 0u) < gen) { /* spin on coherent RMW */ }
        }
        __threadfence();                       // acquire
    }
    __syncthreads();
}

// Single fused kernel: 512 blocks x 256 threads (4 waves).
// Phase 1: blocks [0,250)  -> wsum, 1 wave per weight row (4 rows/block)
//          blocks [250,506)-> proto partials: idx=blk-250, bx=idx&3 (256-col chunk),
//                             by=idx>>2 (32-row chunk); partial colsum + sq
// barrier
// Phase 2: blocks 0..3 finalize colsum; block 4 finalizes proto_sq
// barrier
// Phase 3: 4 samples per wave (512*4*4 = 8192), butterfly reduce, write row.
__global__ void __launch_bounds__(256, 4) kfused(
        const float* __restrict__ x, const float* __restrict__ proto,
        const float* __restrict__ w, const float* __restrict__ bias,
        float* __restrict__ out, float* __restrict__ ws) {
    const int blk = blockIdx.x;
    const int t = threadIdx.x;
    const int wave = t >> 6, lane = t & 63;
    unsigned* bar = (unsigned*)(ws + WS_BAR);

    // ---- Phase 1 ----
    if (blk < 250) {
        const int o = blk * 4 + wave;                          // < 1000
        const float4* row = (const float4*)(w + (size_t)o * PP); // 512 float4
        float s = 0.f;
#pragma unroll
        for (int k = 0; k < 8; ++k) {
            float4 v = row[lane + 64 * k];
            s += v.x + v.y + v.z + v.w;
        }
        for (int off = 32; off > 0; off >>= 1) s += __shfl_down(s, off, 64);
        if (lane == 0) ws[WS_WSUM + o] = s;
    } else if (blk < 506) {
        const int idx = blk - 250;
        const int bx = idx & 3;      // column chunk 0..3
        const int by = idx >> 2;     // row chunk 0..63 (32 rows each)
        const int c = bx * 256 + t;  // column 0..1023
        float csum = 0.f, sq = 0.f;
        const int p0 = by * 32;
#pragma unroll 8
        for (int p = p0; p < p0 + 32; ++p) {
            float v = proto[(size_t)p * LL + c];
            csum += v;
            sq   += v * v;
        }
        ws[WS_PCOL + by * LL + c] = csum;
        __shared__ float red[256];
        red[t] = sq;
        __syncthreads();
        for (int s = 128; s > 0; s >>= 1) {
            if (t < s) red[t] += red[t + s];
            __syncthreads();
        }
        if (t == 0) ws[WS_SQPART + by * 4 + bx] = red[0];
    }

    grid_barrier(bar, 1u);

    // ---- Phase 2 ----
    if (blk < 4) {
        const int c = blk * 256 + t;
        float s = 0.f;
#pragma unroll
        for (int r = 0; r < 64; ++r) s += ws[WS_PCOL + r * LL + c];
        ws[WS_COLSUM + c] = s;
    } else if (blk == 4) {
        __shared__ float red2[256];
        red2[t] = ws[WS_SQPART + t];
        __syncthreads();
        for (int s2 = 128; s2 > 0; s2 >>= 1) {
            if (t < s2) red2[t] += red2[t + s2];
            __syncthreads();
        }
        if (t == 0) ws[WS_PSQ] = red2[0];
    }

    grid_barrier(bar, 2u);

    // ---- Phase 3 ----
    const float psq = ws[WS_PSQ];
    const float4* cs    = (const float4*)(ws + WS_COLSUM);  // 256 float4
    const float4* wsum4 = (const float4*)(ws + WS_WSUM);
    const float4* bias4 = (const float4*)bias;
#pragma unroll
    for (int s = 0; s < 4; ++s) {
        const int b = blk * 16 + wave * 4 + s;               // < 8192
        const float4* xr = (const float4*)(x + (size_t)b * LL); // 256 float4
        float sumsq = 0.f, dotc = 0.f;
#pragma unroll
        for (int k = 0; k < 4; ++k) {
            float4 xv = xr[lane + 64 * k];
            float4 cv = cs[lane + 64 * k];
            sumsq += xv.x * xv.x + xv.y * xv.y + xv.z * xv.z + xv.w * xv.w;
            dotc  += xv.x * cv.x + xv.y * cv.y + xv.z * cv.z + xv.w * cv.w;
        }
        for (int off = 32; off > 0; off >>= 1) {
            sumsq += __shfl_xor(sumsq, off, 64);
            dotc  += __shfl_xor(dotc,  off, 64);
        }
        const float d = sqrtf((float)PP * sumsq - 2.f * dotc + psq);
        float4* orow = (float4*)(out + (size_t)b * OO);      // 250 float4
#pragma unroll
        for (int k = 0; k < 4; ++k) {
            int idx = lane + 64 * k;
            if (idx < 250) {
                float4 wv = wsum4[idx];
                float4 bv = bias4[idx];
                float4 ov;
                ov.x = d * wv.x + bv.x;
                ov.y = d * wv.y + bv.y;
                ov.z = d * wv.z + bv.z;
                ov.w = d * wv.w + bv.w;
                orow[idx] = ov;
            }
        }
    }
}

extern "C" void kernel_launch(void* const* d_in, const int* in_sizes, int n_in,
                              void* d_out, int out_size, void* d_ws, size_t ws_size,
                              hipStream_t stream) {
    const float* input  = (const float*)d_in[0];  // [B, L]
    const float* proto  = (const float*)d_in[1];  // [P, L]
    const float* weight = (const float*)d_in[2];  // [O, P]
    const float* bias   = (const float*)d_in[3];  // [O]
    float* out = (float*)d_out;                   // [B, O]
    float* ws  = (float*)d_ws;

    // Zero the barrier counters (graph-capturable memset node; runs every replay)
    hipMemsetAsync((char*)d_ws + WS_BAR * sizeof(float), 0, 2 * sizeof(unsigned), stream);

    kfused<<<NB, 256, 0, stream>>>(input, proto, weight, bias, out, ws);
}

// Round 5
// 58.075 us; speedup vs baseline: 1.6392x; 1.6392x over previous
//
#include <hip/hip_runtime.h>

// Problem constants (match reference)
#define BB 8192
#define PP 2048
#define LL 1024
#define OO 1000

// ws float offsets
#define WS_COLSUM 0        // [1024] final column sums of prototypes
#define WS_WSUM   1024     // [1000] weight row sums
#define WS_SQP    2048     // [64]   per-block partial sums of proto^2
// everything written before read within the dependency chain; no zero-init needed

// ---- K1: full colsum (64 col-blocks) + sq partials + weight rowsums (250 blocks) ----
// grid 314 x 256.
// Blocks [0,64): block owns 16 columns x all 2048 rows.
//   t -> sr = t>>4 (sub-row 0..15), cl = t&15; col = blk*16+cl.
//   Per iteration a wave covers 4 rows x 16 cols = 4 fully-used 64B segments.
// Blocks [64,314): weight rowsum, 1 wave per row, 4 rows/block, float4 coalesced.
__global__ void __launch_bounds__(256) k1_pre(
        const float* __restrict__ proto, const float* __restrict__ w,
        float* __restrict__ ws) {
    const int blk = blockIdx.x;
    const int t = threadIdx.x;
    if (blk < 64) {
        const int sr = t >> 4;          // 0..15
        const int cl = t & 15;          // 0..15
        const int col = blk * 16 + cl;  // 0..1023
        float csum = 0.f, sq = 0.f;
        for (int r = sr; r < PP; r += 16) {
            float v = proto[(size_t)r * LL + col];
            csum += v;
            sq   += v * v;
        }
        __shared__ float redc[256];
        __shared__ float reds[256];
        redc[t] = csum;
        reds[t] = sq;
        __syncthreads();
        // colsum: threads cl<16 sum over the 16 sub-row groups
        if (t < 16) {
            float s = 0.f;
#pragma unroll
            for (int g = 0; g < 16; ++g) s += redc[g * 16 + t];
            ws[WS_COLSUM + blk * 16 + t] = s;
        }
        // sq: block total
        for (int s2 = 128; s2 > 0; s2 >>= 1) {
            if (t < s2) reds[t] += reds[t + s2];
            __syncthreads();
        }
        if (t == 0) ws[WS_SQP + blk] = reds[0];
    } else {
        const int wave = t >> 6, lane = t & 63;
        const int o = (blk - 64) * 4 + wave;                   // < 1000
        const float4* row = (const float4*)(w + (size_t)o * PP); // 512 float4
        float s = 0.f;
#pragma unroll
        for (int k = 0; k < 8; ++k) {
            float4 v = row[lane + 64 * k];
            s += v.x + v.y + v.z + v.w;
        }
        for (int off = 32; off > 0; off >>= 1) s += __shfl_down(s, off, 64);
        if (lane == 0) ws[WS_WSUM + o] = s;
    }
}

// ---- K2: per-sample distance + output row ---- (8192 blocks x 256)
__global__ void __launch_bounds__(256) k2_main(
        const float* __restrict__ x, const float* __restrict__ bias,
        const float* __restrict__ ws, float* __restrict__ out) {
    const int b = blockIdx.x;
    const int t = threadIdx.x;
    const int wave = t >> 6, lane = t & 63;

    __shared__ float s_psq;
    __shared__ float s_sq[4], s_dc[4];

    // psq: wave 0 butterfly-sums the 64 partials (L2-hot, 256 B)
    if (wave == 0) {
        float p = ws[WS_SQP + lane];
        for (int off = 32; off > 0; off >>= 1) p += __shfl_xor(p, off, 64);
        if (lane == 0) s_psq = p;
    }

    // main single-pass: 1 float4 of x and colsum per thread
    const float4* xr = (const float4*)(x + (size_t)b * LL);   // 256 float4
    const float4* cs = (const float4*)(ws + WS_COLSUM);
    float4 xv = xr[t];
    float4 cv = cs[t];
    float sumsq = xv.x * xv.x + xv.y * xv.y + xv.z * xv.z + xv.w * xv.w;
    float dotc  = xv.x * cv.x + xv.y * cv.y + xv.z * cv.z + xv.w * cv.w;
    for (int off = 32; off > 0; off >>= 1) {
        sumsq += __shfl_xor(sumsq, off, 64);
        dotc  += __shfl_xor(dotc,  off, 64);
    }
    if (lane == 0) { s_sq[wave] = sumsq; s_dc[wave] = dotc; }
    __syncthreads();
    const float ss = s_sq[0] + s_sq[1] + s_sq[2] + s_sq[3];
    const float dc = s_dc[0] + s_dc[1] + s_dc[2] + s_dc[3];
    const float d = sqrtf((float)PP * ss - 2.f * dc + s_psq);

    if (t < 250) {
        float4 wv = ((const float4*)(ws + WS_WSUM))[t];
        float4 bv = ((const float4*)bias)[t];
        float4 ov;
        ov.x = d * wv.x + bv.x;
        ov.y = d * wv.y + bv.y;
        ov.z = d * wv.z + bv.z;
        ov.w = d * wv.w + bv.w;
        ((float4*)(out + (size_t)b * OO))[t] = ov;
    }
}

extern "C" void kernel_launch(void* const* d_in, const int* in_sizes, int n_in,
                              void* d_out, int out_size, void* d_ws, size_t ws_size,
                              hipStream_t stream) {
    const float* input  = (const float*)d_in[0];  // [B, L]
    const float* proto  = (const float*)d_in[1];  // [P, L]
    const float* weight = (const float*)d_in[2];  // [O, P]
    const float* bias   = (const float*)d_in[3];  // [O]
    float* out = (float*)d_out;                   // [B, O]
    float* ws  = (float*)d_ws;

    k1_pre<<<314, 256, 0, stream>>>(proto, weight, ws);
    k2_main<<<BB, 256, 0, stream>>>(input, bias, ws, out);
}

// Round 6
// 50.368 us; speedup vs baseline: 1.8900x; 1.1530x over previous
//
#include <hip/hip_runtime.h>

// Problem constants (match reference)
#define BB 8192
#define PP 2048
#define LL 1024
#define OO 1000

// ws float offsets
#define WS_COLSUM 0        // [1024] final column sums of prototypes
#define WS_WSUM   1024     // [1000] weight row sums
#define WS_PSQ    2048     // [1]    sum of proto^2 (scalar)
#define WS_SQPART 2112     // [256]  per-proto-block sq partials
#define WS_CNT    3072     // 1 uint, zeroed by hipMemsetAsync each call
#define WS_PCOL   4096     // [64][1024] partial colsums

#define NPB 256            // proto-partial blocks

// ---- K1: proto partials + last-block finalize + weight rowsums ----
// grid 506 x 256.
// Blocks [0,256): proto partials. bx=blk&3 (256-col chunk), by=blk>>2 (32-row chunk).
//   Fully coalesced: 256 consecutive floats per row per block.
//   After partials: threadfence + atomicAdd(done); the 256th block finalizes
//   colsum (64 partials per column, fixed order) and psq (LDS tree, fixed order).
// Blocks [256,506): weight rowsum, 1 wave/row, 4 rows/block, float4.
__global__ void __launch_bounds__(256) k1_pre(
        const float* __restrict__ proto, const float* __restrict__ w,
        float* __restrict__ ws) {
    const int blk = blockIdx.x;
    const int t = threadIdx.x;
    if (blk < NPB) {
        const int bx = blk & 3;      // column chunk 0..3
        const int by = blk >> 2;     // row chunk 0..63 (32 rows each)
        const int c = bx * 256 + t;  // column 0..1023
        float csum = 0.f, sq = 0.f;
        const int p0 = by * 32;
#pragma unroll 8
        for (int p = p0; p < p0 + 32; ++p) {
            float v = proto[(size_t)p * LL + c];
            csum += v;
            sq   += v * v;
        }
        ws[WS_PCOL + by * LL + c] = csum;
        __shared__ float red[256];
        red[t] = sq;
        __syncthreads();
        for (int s = 128; s > 0; s >>= 1) {
            if (t < s) red[t] += red[t + s];
            __syncthreads();
        }
        if (t == 0) ws[WS_SQPART + blk] = red[0];

        // ---- deterministic last-block finalize ----
        __shared__ bool is_last;
        __threadfence();  // make partials visible device-wide before signaling
        if (t == 0) {
            unsigned* cnt = (unsigned*)(ws + WS_CNT);
            unsigned old = atomicAdd(cnt, 1u);
            is_last = (old == NPB - 1);
        }
        __syncthreads();
        if (is_last) {
            __threadfence();  // acquire: see all other blocks' partials
            // colsum: thread t owns float4 column group t (cols 4t..4t+3),
            // sums the 64 row-chunk partials in fixed order.
            const float4* pc4 = (const float4*)(ws + WS_PCOL);
            float4 acc = make_float4(0.f, 0.f, 0.f, 0.f);
#pragma unroll
            for (int r = 0; r < 64; ++r) {
                float4 v = pc4[r * 256 + t];
                acc.x += v.x; acc.y += v.y; acc.z += v.z; acc.w += v.w;
            }
            ((float4*)(ws + WS_COLSUM))[t] = acc;
            // psq: LDS tree over the 256 block partials (fixed order)
            __shared__ float red2[256];
            red2[t] = ws[WS_SQPART + t];
            __syncthreads();
            for (int s = 128; s > 0; s >>= 1) {
                if (t < s) red2[t] += red2[t + s];
                __syncthreads();
            }
            if (t == 0) ws[WS_PSQ] = red2[0];
        }
    } else {
        const int wave = t >> 6, lane = t & 63;
        const int o = (blk - NPB) * 4 + wave;                    // < 1000
        const float4* row = (const float4*)(w + (size_t)o * PP); // 512 float4
        float s = 0.f;
#pragma unroll
        for (int k = 0; k < 8; ++k) {
            float4 v = row[lane + 64 * k];
            s += v.x + v.y + v.z + v.w;
        }
        for (int off = 32; off > 0; off >>= 1) s += __shfl_down(s, off, 64);
        if (lane == 0) ws[WS_WSUM + o] = s;
    }
}

// ---- K2: per-sample distance + output row ---- (8192 blocks x 256)
__global__ void __launch_bounds__(256) k2_main(
        const float* __restrict__ x, const float* __restrict__ bias,
        const float* __restrict__ ws, float* __restrict__ out) {
    const int b = blockIdx.x;
    const int t = threadIdx.x;
    const int wave = t >> 6, lane = t & 63;

    const float4* xr = (const float4*)(x + (size_t)b * LL);   // 256 float4
    const float4* cs = (const float4*)(ws + WS_COLSUM);
    float4 xv = xr[t];
    float4 cv = cs[t];
    float sumsq = xv.x * xv.x + xv.y * xv.y + xv.z * xv.z + xv.w * xv.w;
    float dotc  = xv.x * cv.x + xv.y * cv.y + xv.z * cv.z + xv.w * cv.w;
    for (int off = 32; off > 0; off >>= 1) {
        sumsq += __shfl_xor(sumsq, off, 64);
        dotc  += __shfl_xor(dotc,  off, 64);
    }
    __shared__ float s_sq[4], s_dc[4];
    if (lane == 0) { s_sq[wave] = sumsq; s_dc[wave] = dotc; }
    __syncthreads();
    const float ss = s_sq[0] + s_sq[1] + s_sq[2] + s_sq[3];
    const float dc = s_dc[0] + s_dc[1] + s_dc[2] + s_dc[3];
    const float d = sqrtf((float)PP * ss - 2.f * dc + ws[WS_PSQ]);

    if (t < 250) {
        float4 wv = ((const float4*)(ws + WS_WSUM))[t];
        float4 bv = ((const float4*)bias)[t];
        float4 ov;
        ov.x = d * wv.x + bv.x;
        ov.y = d * wv.y + bv.y;
        ov.z = d * wv.z + bv.z;
        ov.w = d * wv.w + bv.w;
        ((float4*)(out + (size_t)b * OO))[t] = ov;
    }
}

extern "C" void kernel_launch(void* const* d_in, const int* in_sizes, int n_in,
                              void* d_out, int out_size, void* d_ws, size_t ws_size,
                              hipStream_t stream) {
    const float* input  = (const float*)d_in[0];  // [B, L]
    const float* proto  = (const float*)d_in[1];  // [P, L]
    const float* weight = (const float*)d_in[2];  // [O, P]
    const float* bias   = (const float*)d_in[3];  // [O]
    float* out = (float*)d_out;                   // [B, O]
    float* ws  = (float*)d_ws;

    // zero the done-counter (graph-legal memset node, runs every replay)
    hipMemsetAsync((char*)d_ws + WS_CNT * sizeof(float), 0, sizeof(unsigned), stream);

    k1_pre<<<506, 256, 0, stream>>>(proto, weight, ws);
    k2_main<<<BB, 256, 0, stream>>>(input, bias, ws, out);
}

// Round 7
// 37.016 us; speedup vs baseline: 2.5718x; 1.3607x over previous
//
#include <hip/hip_runtime.h>

// Problem constants (match reference)
#define BB 8192
#define PP 2048
#define LL 1024
#define OO 1000

// ws BYTE offsets
#define ACC_COLSUM_B 0      // u64[1024] fixed-point colsum accumulators (scale 2^24)
#define ACC_PSQ_B    8192   // u64[1]    fixed-point sum(proto^2)        (scale 2^20)
#define WSUM_B       8448   // float[1000] weight row sums (16B aligned)
#define MEMSET_BYTES 8200   // colsum accs + psq acc

#define CS_SCALE   16777216.0      // 2^24
#define CS_INV     (1.0 / 16777216.0)
#define PSQ_SCALE  1048576.0       // 2^20
#define PSQ_INV    (1.0 / 1048576.0)

// ---- K1: proto partials via deterministic integer atomics + weight rowsums ----
// grid 506 x 256.
// Blocks [0,256): bx=blk&3 (256-col chunk), by=blk>>2 (32-row chunk). Fully
//   coalesced reads. Per-thread colsum partial -> llrint(csum * 2^24) ->
//   atomicAdd(u64). Integer adds are exactly commutative => bit-deterministic.
//   Block sq partial (LDS tree, fixed order) -> one atomicAdd(u64, scale 2^20).
// Blocks [256,506): weight rowsum, 1 wave/row, 4 rows/block, float4 coalesced.
__global__ void __launch_bounds__(256) k1_pre(
        const float* __restrict__ proto, const float* __restrict__ w,
        char* __restrict__ ws) {
    const int blk = blockIdx.x;
    const int t = threadIdx.x;
    if (blk < 256) {
        const int bx = blk & 3;      // column chunk 0..3
        const int by = blk >> 2;     // row chunk 0..63 (32 rows each)
        const int c = bx * 256 + t;  // column 0..1023
        float csum = 0.f, sq = 0.f;
        const int p0 = by * 32;
#pragma unroll 8
        for (int p = p0; p < p0 + 32; ++p) {
            float v = proto[(size_t)p * LL + c];
            csum += v;
            sq   += v * v;
        }
        unsigned long long* colacc = (unsigned long long*)(ws + ACC_COLSUM_B);
        const long long q = llrint((double)csum * CS_SCALE);  // exact in fp64
        atomicAdd(&colacc[c], (unsigned long long)q);

        __shared__ float red[256];
        red[t] = sq;
        __syncthreads();
        for (int s = 128; s > 0; s >>= 1) {
            if (t < s) red[t] += red[t + s];
            __syncthreads();
        }
        if (t == 0) {
            unsigned long long* psqacc = (unsigned long long*)(ws + ACC_PSQ_B);
            const long long qs = llrint((double)red[0] * PSQ_SCALE);
            atomicAdd(psqacc, (unsigned long long)qs);
        }
    } else {
        const int wave = t >> 6, lane = t & 63;
        const int o = (blk - 256) * 4 + wave;                    // < 1000
        const float4* row = (const float4*)(w + (size_t)o * PP); // 512 float4
        float s = 0.f;
#pragma unroll
        for (int k = 0; k < 8; ++k) {
            float4 v = row[lane + 64 * k];
            s += v.x + v.y + v.z + v.w;
        }
        for (int off = 32; off > 0; off >>= 1) s += __shfl_down(s, off, 64);
        if (lane == 0) ((float*)(ws + WSUM_B))[o] = s;
    }
}

// ---- K2: per-sample distance + output row ---- (8192 blocks x 256)
__global__ void __launch_bounds__(256) k2_main(
        const float* __restrict__ x, const float* __restrict__ bias,
        const char* __restrict__ ws, float* __restrict__ out) {
    const int b = blockIdx.x;
    const int t = threadIdx.x;
    const int wave = t >> 6, lane = t & 63;

    // colsum for this thread's 4 columns: two 16B loads of u64 pairs (L2-hot)
    const ulonglong2* colacc2 = (const ulonglong2*)(ws + ACC_COLSUM_B);
    ulonglong2 u01 = colacc2[2 * t];
    ulonglong2 u23 = colacc2[2 * t + 1];
    float4 cv;
    cv.x = (float)((double)(long long)u01.x * CS_INV);
    cv.y = (float)((double)(long long)u01.y * CS_INV);
    cv.z = (float)((double)(long long)u23.x * CS_INV);
    cv.w = (float)((double)(long long)u23.y * CS_INV);

    const float4* xr = (const float4*)(x + (size_t)b * LL);   // 256 float4
    float4 xv = xr[t];
    float sumsq = xv.x * xv.x + xv.y * xv.y + xv.z * xv.z + xv.w * xv.w;
    float dotc  = xv.x * cv.x + xv.y * cv.y + xv.z * cv.z + xv.w * cv.w;
    for (int off = 32; off > 0; off >>= 1) {
        sumsq += __shfl_xor(sumsq, off, 64);
        dotc  += __shfl_xor(dotc,  off, 64);
    }
    __shared__ float s_sq[4], s_dc[4];
    if (lane == 0) { s_sq[wave] = sumsq; s_dc[wave] = dotc; }
    __syncthreads();
    const float ss = s_sq[0] + s_sq[1] + s_sq[2] + s_sq[3];
    const float dc = s_dc[0] + s_dc[1] + s_dc[2] + s_dc[3];
    const float psq = (float)((double)*(const long long*)(ws + ACC_PSQ_B) * PSQ_INV);
    const float d = sqrtf((float)PP * ss - 2.f * dc + psq);

    if (t < 250) {
        float4 wv = ((const float4*)(ws + WSUM_B))[t];
        float4 bv = ((const float4*)bias)[t];
        float4 ov;
        ov.x = d * wv.x + bv.x;
        ov.y = d * wv.y + bv.y;
        ov.z = d * wv.z + bv.z;
        ov.w = d * wv.w + bv.w;
        ((float4*)(out + (size_t)b * OO))[t] = ov;
    }
}

extern "C" void kernel_launch(void* const* d_in, const int* in_sizes, int n_in,
                              void* d_out, int out_size, void* d_ws, size_t ws_size,
                              hipStream_t stream) {
    const float* input  = (const float*)d_in[0];  // [B, L]
    const float* proto  = (const float*)d_in[1];  // [P, L]
    const float* weight = (const float*)d_in[2];  // [O, P]
    const float* bias   = (const float*)d_in[3];  // [O]
    float* out = (float*)d_out;                   // [B, O]
    char* ws   = (char*)d_ws;

    // zero the integer accumulators (graph-legal memset node, runs every replay)
    hipMemsetAsync(ws, 0, MEMSET_BYTES, stream);

    k1_pre<<<506, 256, 0, stream>>>(proto, weight, ws);
    k2_main<<<BB, 256, 0, stream>>>(input, bias, ws, out);
}

// Round 8
// 26.945 us; speedup vs baseline: 3.5330x; 1.3738x over previous
//
#include <hip/hip_runtime.h>

// Problem constants (match reference)
#define BB 8192
#define PP 2048
#define LL 1024
#define OO 1000
#define NPROW 16   // colsum partial row-chunks (128 proto rows each)

// ws float offsets (no init required: K1 writes everything K2 reads)
#define WS_PCOL 0        // [16][1024] partial colsums
#define WS_WSUM 16384    // [1000] weight row sums
#define WS_SQP  17408    // [64]   per-proto-block sq partials

// ---- K1: proto partials + weight rowsums (no atomics, no fences) ----
// grid 314 x 256.
// Blocks [0,64): proto. bx=blk&3 (256-col chunk), by=blk>>2 (128-row chunk).
//   Fully coalesced: wave reads 4x64B segments per row. Writes pcol[by][c],
//   and block sq partial (fixed-order LDS tree) -> sqp[blk].
// Blocks [64,314): weight rowsum, 1 wave/row, 4 rows/block, float4 coalesced.
__global__ void __launch_bounds__(256) k1_pre(
        const float* __restrict__ proto, const float* __restrict__ w,
        float* __restrict__ ws) {
    const int blk = blockIdx.x;
    const int t = threadIdx.x;
    if (blk < 64) {
        const int bx = blk & 3;       // column chunk 0..3
        const int by = blk >> 2;      // row chunk 0..15 (128 rows each)
        const int c = bx * 256 + t;   // column 0..1023
        float csum = 0.f, sq = 0.f;
        const int p0 = by * 128;
#pragma unroll 8
        for (int p = p0; p < p0 + 128; ++p) {
            float v = proto[(size_t)p * LL + c];
            csum += v;
            sq   += v * v;
        }
        ws[WS_PCOL + by * LL + c] = csum;
        __shared__ float red[256];
        red[t] = sq;
        __syncthreads();
        for (int s = 128; s > 0; s >>= 1) {
            if (t < s) red[t] += red[t + s];
            __syncthreads();
        }
        if (t == 0) ws[WS_SQP + blk] = red[0];
    } else {
        const int wave = t >> 6, lane = t & 63;
        const int o = (blk - 64) * 4 + wave;                     // < 1000
        const float4* row = (const float4*)(w + (size_t)o * PP); // 512 float4
        float s = 0.f;
#pragma unroll
        for (int k = 0; k < 8; ++k) {
            float4 v = row[lane + 64 * k];
            s += v.x + v.y + v.z + v.w;
        }
        for (int off = 32; off > 0; off >>= 1) s += __shfl_down(s, off, 64);
        if (lane == 0) ws[WS_WSUM + o] = s;
    }
}

// ---- K2: finalize-in-block + 8 samples per block ---- (1024 blocks x 256)
// Per block: (a) thread t sums the 16 pcol partials for its float4 column
// group (fixed order) -> LDS colsum; (b) wave 0 butterfly-reduces sqp[64]
// -> psq; (c) t<250 stages wsum/bias float4 to LDS; sync; (d) each wave
// processes 2 samples independently (butterfly reduce, float4 output row).
__global__ void __launch_bounds__(256) k2_main(
        const float* __restrict__ x, const float* __restrict__ bias,
        const float* __restrict__ ws, float* __restrict__ out) {
    const int blk = blockIdx.x;
    const int t = threadIdx.x;
    const int wave = t >> 6, lane = t & 63;

    __shared__ float4 s_cs[256];   // colsum, as float4 per column group
    __shared__ float4 s_w[256];    // wsum (250 used)
    __shared__ float4 s_b[256];    // bias (250 used)
    __shared__ float s_psq;

    // (a) colsum finalize: 16 float4 loads per thread, fixed order (L2-hot)
    {
        const float4* pc4 = (const float4*)(ws + WS_PCOL);
        float4 acc = make_float4(0.f, 0.f, 0.f, 0.f);
#pragma unroll
        for (int r = 0; r < NPROW; ++r) {
            float4 v = pc4[r * 256 + t];
            acc.x += v.x; acc.y += v.y; acc.z += v.z; acc.w += v.w;
        }
        s_cs[t] = acc;
    }
    // (b) psq: wave 0, 64-wide butterfly (fixed order)
    if (wave == 0) {
        float p = ws[WS_SQP + lane];
        for (int off = 32; off > 0; off >>= 1) p += __shfl_xor(p, off, 64);
        if (lane == 0) s_psq = p;
    }
    // (c) stage wsum + bias
    if (t < 250) {
        s_w[t] = ((const float4*)(ws + WS_WSUM))[t];
        s_b[t] = ((const float4*)bias)[t];
    }
    __syncthreads();
    const float psq = s_psq;

    // (d) 2 samples per wave, waves independent
#pragma unroll
    for (int s = 0; s < 2; ++s) {
        const int b = blk * 8 + wave * 2 + s;                   // < 8192
        const float4* xr = (const float4*)(x + (size_t)b * LL); // 256 float4
        float sumsq = 0.f, dotc = 0.f;
#pragma unroll
        for (int k = 0; k < 4; ++k) {
            float4 xv = xr[lane + 64 * k];
            float4 cv = s_cs[lane + 64 * k];
            sumsq += xv.x * xv.x + xv.y * xv.y + xv.z * xv.z + xv.w * xv.w;
            dotc  += xv.x * cv.x + xv.y * cv.y + xv.z * cv.z + xv.w * cv.w;
        }
        for (int off = 32; off > 0; off >>= 1) {
            sumsq += __shfl_xor(sumsq, off, 64);
            dotc  += __shfl_xor(dotc,  off, 64);
        }
        const float d = sqrtf((float)PP * sumsq - 2.f * dotc + psq);
        float4* orow = (float4*)(out + (size_t)b * OO);         // 250 float4
#pragma unroll
        for (int k = 0; k < 4; ++k) {
            const int idx = lane + 64 * k;
            if (idx < 250) {
                float4 wv = s_w[idx];
                float4 bv = s_b[idx];
                float4 ov;
                ov.x = d * wv.x + bv.x;
                ov.y = d * wv.y + bv.y;
                ov.z = d * wv.z + bv.z;
                ov.w = d * wv.w + bv.w;
                orow[idx] = ov;
            }
        }
    }
}

extern "C" void kernel_launch(void* const* d_in, const int* in_sizes, int n_in,
                              void* d_out, int out_size, void* d_ws, size_t ws_size,
                              hipStream_t stream) {
    const float* input  = (const float*)d_in[0];  // [B, L]
    const float* proto  = (const float*)d_in[1];  // [P, L]
    const float* weight = (const float*)d_in[2];  // [O, P]
    const float* bias   = (const float*)d_in[3];  // [O]
    float* out = (float*)d_out;                   // [B, O]
    float* ws  = (float*)d_ws;

    k1_pre<<<314, 256, 0, stream>>>(proto, weight, ws);
    k2_main<<<1024, 256, 0, stream>>>(input, bias, ws, out);
}